// Round 6
// baseline (350.863 us; speedup 1.0000x reference)
//
#include <hip/hip_runtime.h>
#include <stdint.h>

#define DM 1024
#define NH 16
#define DKH 64
#define BB 4
#define SS 4096
#define MM (BB*SS)   // 16384

typedef __bf16 bf16x8 __attribute__((ext_vector_type(8)));
typedef float f32x4 __attribute__((ext_vector_type(4)));

__device__ __forceinline__ float bf2f(ushort u) {
  union { uint32_t i; float f; } v; v.i = ((uint32_t)u) << 16; return v.f;
}
__device__ __forceinline__ ushort f2bf(float f) {
  union { float f; uint32_t i; } v; v.f = f;
  uint32_t x = v.i;
  uint32_t r = (x + 0x7fffu + ((x >> 16) & 1u)) >> 16;
  return (ushort)r;
}
__device__ __forceinline__ void unpack8(uint4 u, float* o) {
  o[0] = bf2f((ushort)(u.x & 0xffff)); o[1] = bf2f((ushort)(u.x >> 16));
  o[2] = bf2f((ushort)(u.y & 0xffff)); o[3] = bf2f((ushort)(u.y >> 16));
  o[4] = bf2f((ushort)(u.z & 0xffff)); o[5] = bf2f((ushort)(u.z >> 16));
  o[6] = bf2f((ushort)(u.w & 0xffff)); o[7] = bf2f((ushort)(u.w >> 16));
}
__device__ __forceinline__ void unpack4(uint2 u, float* o) {
  o[0] = bf2f((ushort)(u.x & 0xffff)); o[1] = bf2f((ushort)(u.x >> 16));
  o[2] = bf2f((ushort)(u.y & 0xffff)); o[3] = bf2f((ushort)(u.y >> 16));
}

#define GLL16(g, l) __builtin_amdgcn_global_load_lds( \
    (__attribute__((address_space(1))) void*)(g), \
    (__attribute__((address_space(3))) void*)(l), 16, 0, 0)

// ---------------- fused cast: 4 weight matrices in one launch ----------------
__global__ void cast_w4(const float* __restrict__ s0, const float* __restrict__ s1,
                        const float* __restrict__ s2, const float* __restrict__ s3,
                        ushort* __restrict__ d0, ushort* __restrict__ d1,
                        ushort* __restrict__ d2, ushort* __restrict__ d3) {
  const int which = blockIdx.x >> 10;              // 1024 blocks per tensor
  const int i = ((blockIdx.x & 1023) * 256 + threadIdx.x) * 4;
  const float* src = which == 0 ? s0 : (which == 1 ? s1 : (which == 2 ? s2 : s3));
  ushort* dst = which == 0 ? d0 : (which == 1 ? d1 : (which == 2 ? d2 : d3));
  float4 v = *reinterpret_cast<const float4*>(src + i);
  ushort4 o; o.x = f2bf(v.x); o.y = f2bf(v.y); o.z = f2bf(v.z); o.w = f2bf(v.w);
  *reinterpret_cast<ushort4*>(dst + i) = o;
}

// ---------------- 256x256 2-phase bf16 GEMM: C[m,n] = sum_k A[m,k]*Bw[n,k] + bias[n]
// 512 threads = 8 waves (2M x 4N), BK=64, double-buffered 128 KiB LDS,
// stage(next) issued BEFORE compute(cur), ONE __syncthreads per K-step.
// AF32: A is fp32 in HBM; staged via regs (issue-early) -> cvt+ds_write (write-late,
//       after the MFMA phase hides the load latency)  [T14]
// MODE 0: bf16 out + elu+1 ; MODE 1: bf16 out ; MODE 2: f32 out
template<int MODE, bool AF32>
__global__ __launch_bounds__(512, 2) void gemm256(
    const void* __restrict__ Ain, const ushort* __restrict__ Bw,
    const float* __restrict__ bias, void* __restrict__ Cout,
    const int K, const int N) {
  __shared__ ushort Abuf[2][256 * 64];   // 64 KiB
  __shared__ ushort Bbuf[2][256 * 64];   // 64 KiB
  const ushort* A16 = (const ushort*)Ain;
  const float*  A32 = (const float*)Ain;
  const int t = threadIdx.x;
  const int lane = t & 63;
  const int w = t >> 6;
  // XCD-aware swizzle (nwg = 256, %8 == 0 -> bijective)
  const int id = blockIdx.y * gridDim.x + blockIdx.x;
  const int cpx = (gridDim.x * gridDim.y) >> 3;
  const int swz = (id & 7) * cpx + (id >> 3);
  const int bx = swz % gridDim.x;
  const int by = swz / gridDim.x;
  const int m0 = by * 256, n0 = bx * 256;
  const int wm = w >> 2, wn = w & 3;              // wave tile: 128 x 64
  const int fr = lane & 15, kq = (lane >> 4) * 8;

  // staging: thread t covers rows (t>>3)+l*64, cols (t&7)*8..+7, l=0..3
  const size_t gA = (size_t)(m0 + (t >> 3)) * K + (t & 7) * 8;
  const size_t gB = (size_t)(n0 + (t >> 3)) * K + (t & 7) * 8;
  const int ldsbase = w * 512;   // gload_lds: wave-uniform base, +lane*16B by HW
  const int ldsA = 8 * t;        // == ldsbase + lane*8 elements (explicit ds_write)

  f32x4 acc[8][4] = {};
  const int arow = wm * 128 + fr;
  const int brow = wn * 64 + fr;

  const int NT = K >> 6;   // 16
  int cur = 0;
  uint4 areg[8];

  // ---- prologue: stage tile 0 into buf 0
  if constexpr (AF32) {
#pragma unroll
    for (int l = 0; l < 4; ++l) {
      const float* p = A32 + gA + (size_t)l * 64 * K;
      areg[2 * l]     = *reinterpret_cast<const uint4*>(p);
      areg[2 * l + 1] = *reinterpret_cast<const uint4*>(p + 4);
    }
  } else {
#pragma unroll
    for (int l = 0; l < 4; ++l)
      GLL16(A16 + gA + (size_t)l * 64 * K, &Abuf[0][ldsbase + l * 4096]);
  }
#pragma unroll
  for (int l = 0; l < 4; ++l)
    GLL16(Bw + gB + (size_t)l * 64 * K, &Bbuf[0][ldsbase + l * 4096]);
  if constexpr (AF32) {
#pragma unroll
    for (int l = 0; l < 4; ++l) {
      const float* f = reinterpret_cast<const float*>(&areg[2 * l]);
      ushort tmp[8];
#pragma unroll
      for (int j = 0; j < 8; ++j) tmp[j] = f2bf(f[j]);
      *reinterpret_cast<uint4*>(&Abuf[0][ldsA + l * 4096]) = *reinterpret_cast<uint4*>(tmp);
    }
  }
  __syncthreads();

  for (int kt = 0; kt < NT - 1; ++kt) {
    const size_t k0 = (size_t)(kt + 1) * 64;
    // phase 1: issue next tile's loads (A->regs or A->LDS, B->LDS)
    if constexpr (AF32) {
#pragma unroll
      for (int l = 0; l < 4; ++l) {
        const float* p = A32 + gA + (size_t)l * 64 * K + k0;
        areg[2 * l]     = *reinterpret_cast<const uint4*>(p);
        areg[2 * l + 1] = *reinterpret_cast<const uint4*>(p + 4);
      }
    } else {
#pragma unroll
      for (int l = 0; l < 4; ++l)
        GLL16(A16 + gA + (size_t)l * 64 * K + k0, &Abuf[cur ^ 1][ldsbase + l * 4096]);
    }
#pragma unroll
    for (int l = 0; l < 4; ++l)
      GLL16(Bw + gB + (size_t)l * 64 * K + k0, &Bbuf[cur ^ 1][ldsbase + l * 4096]);
    // phase 2: compute current tile (hides A-load latency)
#pragma unroll
    for (int ks = 0; ks < 2; ++ks) {
      bf16x8 a[8], b[4];
#pragma unroll
      for (int mi = 0; mi < 8; ++mi)
        a[mi] = *reinterpret_cast<const bf16x8*>(&Abuf[cur][(arow + mi * 16) * 64 + ks * 32 + kq]);
#pragma unroll
      for (int ni = 0; ni < 4; ++ni)
        b[ni] = *reinterpret_cast<const bf16x8*>(&Bbuf[cur][(brow + ni * 16) * 64 + ks * 32 + kq]);
#pragma unroll
      for (int mi = 0; mi < 8; ++mi)
#pragma unroll
        for (int ni = 0; ni < 4; ++ni)
          acc[mi][ni] = __builtin_amdgcn_mfma_f32_16x16x32_bf16(a[mi], b[ni], acc[mi][ni], 0, 0, 0);
    }
    // phase 3 (write-late): cvt staged A regs -> LDS for next tile
    if constexpr (AF32) {
#pragma unroll
      for (int l = 0; l < 4; ++l) {
        const float* f = reinterpret_cast<const float*>(&areg[2 * l]);
        ushort tmp[8];
#pragma unroll
        for (int j = 0; j < 8; ++j) tmp[j] = f2bf(f[j]);
        *reinterpret_cast<uint4*>(&Abuf[cur ^ 1][ldsA + l * 4096]) = *reinterpret_cast<uint4*>(tmp);
      }
    }
    __syncthreads();   // next tile resident, cur consumed
    cur ^= 1;
  }
  // epilogue K-step (no prefetch)
#pragma unroll
  for (int ks = 0; ks < 2; ++ks) {
    bf16x8 a[8], b[4];
#pragma unroll
    for (int mi = 0; mi < 8; ++mi)
      a[mi] = *reinterpret_cast<const bf16x8*>(&Abuf[cur][(arow + mi * 16) * 64 + ks * 32 + kq]);
#pragma unroll
    for (int ni = 0; ni < 4; ++ni)
      b[ni] = *reinterpret_cast<const bf16x8*>(&Bbuf[cur][(brow + ni * 16) * 64 + ks * 32 + kq]);
#pragma unroll
    for (int mi = 0; mi < 8; ++mi)
#pragma unroll
      for (int ni = 0; ni < 4; ++ni)
        acc[mi][ni] = __builtin_amdgcn_mfma_f32_16x16x32_bf16(a[mi], b[ni], acc[mi][ni], 0, 0, 0);
  }

  // epilogue: bias (+elu) + store
  const int fq = (lane >> 4) * 4;
  float bv[4];
#pragma unroll
  for (int ni = 0; ni < 4; ++ni) bv[ni] = bias[n0 + wn * 64 + ni * 16 + fr];
#pragma unroll
  for (int mi = 0; mi < 8; ++mi) {
#pragma unroll
    for (int ni = 0; ni < 4; ++ni) {
      const int c = n0 + wn * 64 + ni * 16 + fr;
#pragma unroll
      for (int q = 0; q < 4; ++q) {
        const int r = m0 + wm * 128 + mi * 16 + fq + q;
        float v = acc[mi][ni][q] + bv[ni];
        if constexpr (MODE == 0) v = (v > 0.f) ? (v + 1.f) : __expf(v);
        if constexpr (MODE == 2) {
          reinterpret_cast<float*>(Cout)[(size_t)r * N + c] = v;
        } else {
          reinterpret_cast<ushort*>(Cout)[(size_t)r * N + c] = f2bf(v);
        }
      }
    }
  }
}

// ---------------- KV partials: per wave, KVp[slab][bh][64][64] = sum_{s in range} K[s,d]*V[s,e]
__global__ __launch_bounds__(256) void kv_kernel(
    const ushort* __restrict__ Kp, const ushort* __restrict__ Vp,
    float* __restrict__ KVpart, float* __restrict__ Kspart) {
  __shared__ ushort KL[4][64][64];
  __shared__ ushort VL[4][64][64];
  const int bh = blockIdx.x;
  const int chunk = blockIdx.y;
  const int b = bh >> 4, h = bh & 15;
  const int t = threadIdx.x;
  const int w = t >> 6, lane = t & 63;
  const int d0 = (lane >> 2) * 4;
  const int e0 = (lane & 3) * 16;
  const int srow = lane >> 3;
  const int scol = (lane & 7) * 8;

  float acc[4][16] = {};
  float ks[4] = {};

  ushort* lk = &KL[w][0][0];
  ushort* lv = &VL[w][0][0];
  const int s_wave = chunk * 512 + w * 128;

  for (int tile = 0; tile < 2; ++tile) {
    const int s0 = s_wave + tile * 64;
    const size_t gbase = (size_t)(b * SS + s0 + srow) * DM + h * 64 + scol;
    asm volatile("s_waitcnt lgkmcnt(0)" ::: "memory");
#pragma unroll
    for (int it = 0; it < 8; ++it) {
      GLL16(Kp + gbase + (size_t)it * 8 * DM, lk + it * 512);
      GLL16(Vp + gbase + (size_t)it * 8 * DM, lv + it * 512);
    }
    asm volatile("s_waitcnt vmcnt(0)" ::: "memory");
    __builtin_amdgcn_sched_barrier(0);

#pragma unroll 2
    for (int s = 0; s < 64; ++s) {
      float kf[4], vf[16];
      uint2 uk = *reinterpret_cast<const uint2*>(&KL[w][s][d0]);
      uint4 uv0 = *reinterpret_cast<const uint4*>(&VL[w][s][e0]);
      uint4 uv1 = *reinterpret_cast<const uint4*>(&VL[w][s][e0 + 8]);
      unpack4(uk, kf);
      unpack8(uv0, vf);
      unpack8(uv1, vf + 8);
#pragma unroll
      for (int i = 0; i < 4; ++i) {
        ks[i] += kf[i];
#pragma unroll
        for (int j = 0; j < 16; ++j) acc[i][j] += kf[i] * vf[j];
      }
    }
  }

  const int slab = chunk * 4 + w;
  float* kvp = KVpart + ((size_t)slab * 64 + bh) * 4096;
#pragma unroll
  for (int i = 0; i < 4; ++i) {
#pragma unroll
    for (int j4 = 0; j4 < 4; ++j4) {
      float4 v = { acc[i][j4*4+0], acc[i][j4*4+1], acc[i][j4*4+2], acc[i][j4*4+3] };
      *reinterpret_cast<float4*>(kvp + (d0 + i) * 64 + e0 + j4 * 4) = v;
    }
  }
  // 4 lanes sharing d0 hold IDENTICAL sums — write one copy, no reduction.
  if ((lane & 3) == 0) {
    float4 v = { ks[0], ks[1], ks[2], ks[3] };
    *reinterpret_cast<float4*>(Kspart + (size_t)slab * 4096 + bh * 64 + d0) = v;
  }
}

// ---------------- reduce 32 partials -> KVTx bf16 [bh][80][64]:
// rows 0..63 = KV^T (row e, col d), row 64 = Ksum, rows 65..79 = 0 (pre-memset).
__global__ __launch_bounds__(256) void kvreduce_kernel(
    const float* __restrict__ KVpart, const float* __restrict__ Kspart,
    ushort* __restrict__ KVTx) {
  const int idx = blockIdx.x * 256 + threadIdx.x;
  const int bh = idx >> 12;
  const int d = (idx >> 6) & 63;
  const int e = idx & 63;
  float s = 0.f;
#pragma unroll
  for (int c = 0; c < 32; ++c) s += KVpart[(size_t)c * (64 * 4096) + idx];
  KVTx[(size_t)bh * 5120 + e * 64 + d] = f2bf(s);
  if (idx < 64 * 64) {
    float s2 = 0.f;
#pragma unroll
    for (int c = 0; c < 32; ++c) s2 += Kspart[(size_t)c * 4096 + idx];
    KVTx[(size_t)(idx >> 6) * 5120 + 4096 + (idx & 63)] = f2bf(s2);
  }
}

// ---------------- Z via MFMA: per (bh, 128-row tile). 4 waves x 32 rows.
__global__ __launch_bounds__(256) void z_mfma_kernel(
    const ushort* __restrict__ Qp, const ushort* __restrict__ KVTx,
    ushort* __restrict__ Zn) {
  const int bh = blockIdx.y;
  const int b = bh >> 4, h = bh & 15;
  const int t = threadIdx.x;
  const int w = t >> 6, lane = t & 63;
  const int fr = lane & 15;
  const int kq = (lane >> 4) * 8;
  const int s0 = blockIdx.x * 128 + w * 32;

  const ushort* kvb = KVTx + (size_t)bh * 5120;
  bf16x8 bfrag[5][2];
#pragma unroll
  for (int ni = 0; ni < 5; ++ni)
#pragma unroll
    for (int ks = 0; ks < 2; ++ks)
      bfrag[ni][ks] = *reinterpret_cast<const bf16x8*>(kvb + (ni * 16 + fr) * 64 + ks * 32 + kq);

  f32x4 acc[2][5] = {};
  const size_t arow = (size_t)(b * SS + s0 + fr) * DM + h * 64;
#pragma unroll
  for (int mi = 0; mi < 2; ++mi) {
#pragma unroll
    for (int ks = 0; ks < 2; ++ks) {
      bf16x8 a = *reinterpret_cast<const bf16x8*>(Qp + arow + (size_t)mi * 16 * DM + ks * 32 + kq);
#pragma unroll
      for (int ni = 0; ni < 5; ++ni)
        acc[mi][ni] = __builtin_amdgcn_mfma_f32_16x16x32_bf16(a, bfrag[ni][ks], acc[mi][ni], 0, 0, 0);
    }
  }

#pragma unroll
  for (int mi = 0; mi < 2; ++mi) {
#pragma unroll
    for (int q = 0; q < 4; ++q) {
      const float dv = __shfl(acc[mi][4][q], lane & 48);
      const float inv = 1.f / (dv + 1e-6f);
      const int r = s0 + mi * 16 + (lane >> 4) * 4 + q;
      ushort* orow = Zn + (size_t)(b * SS + r) * DM + h * 64;
#pragma unroll
      for (int ni = 0; ni < 4; ++ni)
        orow[ni * 16 + fr] = f2bf(acc[mi][ni][q] * inv);
    }
  }
}

extern "C" void kernel_launch(void* const* d_in, const int* in_sizes, int n_in,
                              void* d_out, int out_size, void* d_ws, size_t ws_size,
                              hipStream_t stream) {
  const float* query = (const float*)d_in[0];
  const float* key_  = (const float*)d_in[1];
  const float* value = (const float*)d_in[2];
  const float* w_q = (const float*)d_in[3];
  const float* b_q = (const float*)d_in[4];
  const float* w_k = (const float*)d_in[5];
  const float* b_k = (const float*)d_in[6];
  const float* w_v = (const float*)d_in[7];
  const float* b_v = (const float*)d_in[8];
  const float* w_o = (const float*)d_in[9];
  const float* b_o = (const float*)d_in[10];

  char* ws = (char*)d_ws;
  const size_t NX = (size_t)MM * DM;            // 16,777,216
  ushort* Wq = (ushort*)ws; ws += (size_t)DM * DM * 2;
  ushort* Wk = (ushort*)ws; ws += (size_t)DM * DM * 2;
  ushort* Wv = (ushort*)ws; ws += (size_t)DM * DM * 2;
  ushort* Wo = (ushort*)ws; ws += (size_t)DM * DM * 2;
  ushort* Qp = (ushort*)ws; ws += NX * 2;
  ushort* Kp = (ushort*)ws; ws += NX * 2;
  ushort* Vp = (ushort*)ws; ws += NX * 2;
  float*  KVpart = (float*)ws; ws += (size_t)32 * 64 * 4096 * 4;  // 32 MiB
  float*  Kspart = (float*)ws; ws += (size_t)32 * 4096 * 4;       // 512 KiB
  ushort* KVTx = (ushort*)ws; ws += (size_t)64 * 80 * 64 * 2;     // 640 KiB
  ushort* Zn = (ushort*)ws; ws += NX * 2;

  cast_w4<<<4 * 1024, 256, 0, stream>>>(w_q, w_k, w_v, w_o, Wq, Wk, Wv, Wo);

  dim3 gg(DM / 256, MM / 256);   // (4, 64)
  gemm256<0, true><<<gg, 512, 0, stream>>>(query, Wq, b_q, Qp, DM, DM);
  gemm256<0, true><<<gg, 512, 0, stream>>>(key_,  Wk, b_k, Kp, DM, DM);
  gemm256<1, true><<<gg, 512, 0, stream>>>(value, Wv, b_v, Vp, DM, DM);

  kv_kernel<<<dim3(64, 8), 256, 0, stream>>>(Kp, Vp, KVpart, Kspart);
  hipMemsetAsync(KVTx, 0, (size_t)64 * 80 * 64 * 2, stream);   // zero rows 65..79
  kvreduce_kernel<<<1024, 256, 0, stream>>>(KVpart, Kspart, KVTx);
  z_mfma_kernel<<<dim3(32, 64), 256, 0, stream>>>(Qp, KVTx, Zn);

  gemm256<2, false><<<gg, 512, 0, stream>>>(Zn, Wo, b_o, d_out, DM, DM);
}

// Round 7
// 294.030 us; speedup vs baseline: 1.1933x; 1.1933x over previous
//
#include <hip/hip_runtime.h>
#include <stdint.h>

#define DM 1024
#define NH 16
#define DKH 64
#define BB 4
#define SS 4096
#define MM (BB*SS)   // 16384

typedef __bf16 bf16x8 __attribute__((ext_vector_type(8)));
typedef float f32x4 __attribute__((ext_vector_type(4)));

__device__ __forceinline__ float bf2f(ushort u) {
  union { uint32_t i; float f; } v; v.i = ((uint32_t)u) << 16; return v.f;
}
__device__ __forceinline__ ushort f2bf(float f) {
  union { float f; uint32_t i; } v; v.f = f;
  uint32_t x = v.i;
  uint32_t r = (x + 0x7fffu + ((x >> 16) & 1u)) >> 16;
  return (ushort)r;
}
__device__ __forceinline__ void unpack8(uint4 u, float* o) {
  o[0] = bf2f((ushort)(u.x & 0xffff)); o[1] = bf2f((ushort)(u.x >> 16));
  o[2] = bf2f((ushort)(u.y & 0xffff)); o[3] = bf2f((ushort)(u.y >> 16));
  o[4] = bf2f((ushort)(u.z & 0xffff)); o[5] = bf2f((ushort)(u.z >> 16));
  o[6] = bf2f((ushort)(u.w & 0xffff)); o[7] = bf2f((ushort)(u.w >> 16));
}
__device__ __forceinline__ void unpack4(uint2 u, float* o) {
  o[0] = bf2f((ushort)(u.x & 0xffff)); o[1] = bf2f((ushort)(u.x >> 16));
  o[2] = bf2f((ushort)(u.y & 0xffff)); o[3] = bf2f((ushort)(u.y >> 16));
}

#define GLL16(g, l) __builtin_amdgcn_global_load_lds( \
    (__attribute__((address_space(1))) void*)(g), \
    (__attribute__((address_space(3))) void*)(l), 16, 0, 0)

// ---------------- fused cast fp32 -> bf16, grid-strided (3 big inputs) ----------------
__global__ void cast3(const float* __restrict__ s0, const float* __restrict__ s1,
                      const float* __restrict__ s2, ushort* __restrict__ d0,
                      ushort* __restrict__ d1, ushort* __restrict__ d2) {
  const int which = blockIdx.x >> 10;        // 1024 blocks per tensor
  const int bid = blockIdx.x & 1023;
  const float* __restrict__ src = which == 0 ? s0 : (which == 1 ? s1 : s2);
  ushort* __restrict__ dst = which == 0 ? d0 : (which == 1 ? d1 : d2);
  const size_t NXE = (size_t)MM * DM;
  const size_t stride = (size_t)1024 * 256 * 8;
  for (size_t i = ((size_t)bid * 256 + threadIdx.x) * 8; i < NXE; i += stride) {
    float4 v0 = *reinterpret_cast<const float4*>(src + i);
    float4 v1 = *reinterpret_cast<const float4*>(src + i + 4);
    ushort tmp[8] = { f2bf(v0.x), f2bf(v0.y), f2bf(v0.z), f2bf(v0.w),
                      f2bf(v1.x), f2bf(v1.y), f2bf(v1.z), f2bf(v1.w) };
    *reinterpret_cast<uint4*>(dst + i) = *reinterpret_cast<uint4*>(tmp);
  }
}
// ---------------- fused cast: 4 weight matrices in one launch ----------------
__global__ void cast_w4(const float* __restrict__ s0, const float* __restrict__ s1,
                        const float* __restrict__ s2, const float* __restrict__ s3,
                        ushort* __restrict__ d0, ushort* __restrict__ d1,
                        ushort* __restrict__ d2, ushort* __restrict__ d3) {
  const int which = blockIdx.x >> 10;              // 1024 blocks per tensor
  const int i = ((blockIdx.x & 1023) * 256 + threadIdx.x) * 4;
  const float* src = which == 0 ? s0 : (which == 1 ? s1 : (which == 2 ? s2 : s3));
  ushort* dst = which == 0 ? d0 : (which == 1 ? d1 : (which == 2 ? d2 : d3));
  float4 v = *reinterpret_cast<const float4*>(src + i);
  ushort4 o; o.x = f2bf(v.x); o.y = f2bf(v.y); o.z = f2bf(v.z); o.w = f2bf(v.w);
  *reinterpret_cast<ushort4*>(dst + i) = o;
}

// ---------------- 256x256 counted-vmcnt pipelined bf16 GEMM ----------------
// C[m,n] = sum_k A[m,k]*Bw[n,k] + bias[n].  512 thr = 8 waves (2M x 4N), BK=32,
// 4 LDS buffers (128 KiB): compute tile p while tiles p+1..p+3 stream in.
// Per phase: 12 swizzled ds_read_b128 + stage(p+3) + 32 MFMA (setprio) +
// s_waitcnt vmcnt(8) [never 0 until drain] + raw s_barrier.   [T2+T3+T4+T5]
// LDS swizzle: 16B-slot ^= row&3 (bijective); global source pre-swizzled since
// global_load_lds writes linearly (rule #21).
// MODE 0: bf16 out + elu+1 ; MODE 1: bf16 out ; MODE 2: f32 out
template<int MODE>
__global__ __launch_bounds__(512, 2) void gemm8p(
    const ushort* __restrict__ A, const ushort* __restrict__ Bw,
    const float* __restrict__ bias, void* __restrict__ Cout) {
  constexpr int K = DM, N = DM;
  constexpr int NT = K / 32;          // 32 K-tiles
  __shared__ ushort smem[4][2][256 * 32];   // [buf][A|B][row*32+col] : 128 KiB
  const int t = threadIdx.x;
  const int lane = t & 63;
  const int w = t >> 6;
  // XCD-aware swizzle (nwg = 4*64 = 256, %8==0 -> bijective)
  const int id = blockIdx.y * gridDim.x + blockIdx.x;
  const int cpx = (gridDim.x * gridDim.y) >> 3;
  const int swz = (id & 7) * cpx + (id >> 3);
  const int bx = swz % gridDim.x;
  const int by = swz / gridDim.x;
  const int m0 = by * 256, n0 = bx * 256;
  const int wm = w >> 2, wn = w & 3;        // wave tile: 128 x 64
  const int fr = lane & 15;
  const int slot = lane >> 4;               // 16B slot 0..3 within 64B row

  // staging: thread t covers rows (t>>2)+l*128, global col pre-swizzled
  const int gsw = ((t & 3) ^ ((t >> 2) & 3)) * 8;   // elements
  const size_t baseA = (size_t)(m0 + (t >> 2)) * K + gsw;
  const size_t baseB = (size_t)(n0 + (t >> 2)) * K + gsw;
  const int ldsoff = w * 512;               // elements; +lane*16B by HW

  f32x4 acc[8][4] = {};

#define STAGE(tile) { \
    const int _b = (tile) & 3; const size_t _k = (size_t)(tile) * 32; \
    GLL16(A + baseA + _k, &smem[_b][0][ldsoff]); \
    GLL16(A + baseA + (size_t)128 * K + _k, &smem[_b][0][4096 + ldsoff]); \
    GLL16(Bw + baseB + _k, &smem[_b][1][ldsoff]); \
    GLL16(Bw + baseB + (size_t)128 * K + _k, &smem[_b][1][4096 + ldsoff]); }

  // prologue: tiles 0,1,2 in flight (12 loads/thread)
  STAGE(0); STAGE(1); STAGE(2);
  asm volatile("s_waitcnt vmcnt(8)" ::: "memory");   // tile 0 resident
  __builtin_amdgcn_s_barrier();
  __builtin_amdgcn_sched_barrier(0);

  for (int p = 0; p < NT; ++p) {
    const ushort* At = &smem[p & 3][0][0];
    const ushort* Bt = &smem[p & 3][1][0];
    bf16x8 bfr[4], afr[8];
#pragma unroll
    for (int ni = 0; ni < 4; ++ni) {
      const int row = wn * 64 + ni * 16 + fr;
      bfr[ni] = *reinterpret_cast<const bf16x8*>(Bt + row * 32 + ((slot ^ (fr & 3)) << 3));
    }
#pragma unroll
    for (int mi = 0; mi < 8; ++mi) {
      const int row = wm * 128 + mi * 16 + fr;
      afr[mi] = *reinterpret_cast<const bf16x8*>(At + row * 32 + ((slot ^ (fr & 3)) << 3));
    }
    if (p + 3 < NT) STAGE(p + 3);
    __builtin_amdgcn_s_setprio(1);
#pragma unroll
    for (int mi = 0; mi < 8; ++mi)
#pragma unroll
      for (int ni = 0; ni < 4; ++ni)
        acc[mi][ni] = __builtin_amdgcn_mfma_f32_16x16x32_bf16(afr[mi], bfr[ni], acc[mi][ni], 0, 0, 0);
    __builtin_amdgcn_s_setprio(0);
    if (p < NT - 1) {
      if (p < NT - 3)       asm volatile("s_waitcnt vmcnt(8)" ::: "memory");  // tile p+1 landed, 2 tiles in flight
      else if (p == NT - 3) asm volatile("s_waitcnt vmcnt(4)" ::: "memory");
      else                  asm volatile("s_waitcnt vmcnt(0)" ::: "memory");
      __builtin_amdgcn_s_barrier();
      __builtin_amdgcn_sched_barrier(0);
    }
  }
#undef STAGE

  // epilogue: bias (+elu) + store
  const int fq = (lane >> 4) * 4;
  float bv[4];
#pragma unroll
  for (int ni = 0; ni < 4; ++ni) bv[ni] = bias[n0 + wn * 64 + ni * 16 + fr];
#pragma unroll
  for (int mi = 0; mi < 8; ++mi) {
#pragma unroll
    for (int ni = 0; ni < 4; ++ni) {
      const int c = n0 + wn * 64 + ni * 16 + fr;
#pragma unroll
      for (int q = 0; q < 4; ++q) {
        const int r = m0 + wm * 128 + mi * 16 + fq + q;
        float v = acc[mi][ni][q] + bv[ni];
        if constexpr (MODE == 0) v = (v > 0.f) ? (v + 1.f) : __expf(v);
        if constexpr (MODE == 2) {
          reinterpret_cast<float*>(Cout)[(size_t)r * N + c] = v;
        } else {
          reinterpret_cast<ushort*>(Cout)[(size_t)r * N + c] = f2bf(v);
        }
      }
    }
  }
}

// ---------------- KV partials: per wave, KVp[slab][bh][64][64] = sum_{s in range} K[s,d]*V[s,e]
__global__ __launch_bounds__(256) void kv_kernel(
    const ushort* __restrict__ Kp, const ushort* __restrict__ Vp,
    float* __restrict__ KVpart, float* __restrict__ Kspart) {
  __shared__ ushort KL[4][64][64];
  __shared__ ushort VL[4][64][64];
  const int bh = blockIdx.x;
  const int chunk = blockIdx.y;
  const int b = bh >> 4, h = bh & 15;
  const int t = threadIdx.x;
  const int w = t >> 6, lane = t & 63;
  const int d0 = (lane >> 2) * 4;
  const int e0 = (lane & 3) * 16;
  const int srow = lane >> 3;
  const int scol = (lane & 7) * 8;

  float acc[4][16] = {};
  float ks[4] = {};

  ushort* lk = &KL[w][0][0];
  ushort* lv = &VL[w][0][0];
  const int s_wave = chunk * 512 + w * 128;

  for (int tile = 0; tile < 2; ++tile) {
    const int s0 = s_wave + tile * 64;
    const size_t gbase = (size_t)(b * SS + s0 + srow) * DM + h * 64 + scol;
    asm volatile("s_waitcnt lgkmcnt(0)" ::: "memory");
#pragma unroll
    for (int it = 0; it < 8; ++it) {
      GLL16(Kp + gbase + (size_t)it * 8 * DM, lk + it * 512);
      GLL16(Vp + gbase + (size_t)it * 8 * DM, lv + it * 512);
    }
    asm volatile("s_waitcnt vmcnt(0)" ::: "memory");
    __builtin_amdgcn_sched_barrier(0);

#pragma unroll 2
    for (int s = 0; s < 64; ++s) {
      float kf[4], vf[16];
      uint2 uk = *reinterpret_cast<const uint2*>(&KL[w][s][d0]);
      uint4 uv0 = *reinterpret_cast<const uint4*>(&VL[w][s][e0]);
      uint4 uv1 = *reinterpret_cast<const uint4*>(&VL[w][s][e0 + 8]);
      unpack4(uk, kf);
      unpack8(uv0, vf);
      unpack8(uv1, vf + 8);
#pragma unroll
      for (int i = 0; i < 4; ++i) {
        ks[i] += kf[i];
#pragma unroll
        for (int j = 0; j < 16; ++j) acc[i][j] += kf[i] * vf[j];
      }
    }
  }

  const int slab = chunk * 4 + w;
  float* kvp = KVpart + ((size_t)slab * 64 + bh) * 4096;
#pragma unroll
  for (int i = 0; i < 4; ++i) {
#pragma unroll
    for (int j4 = 0; j4 < 4; ++j4) {
      float4 v = { acc[i][j4*4+0], acc[i][j4*4+1], acc[i][j4*4+2], acc[i][j4*4+3] };
      *reinterpret_cast<float4*>(kvp + (d0 + i) * 64 + e0 + j4 * 4) = v;
    }
  }
  // 4 lanes sharing d0 hold IDENTICAL sums — write one copy, no reduction.
  if ((lane & 3) == 0) {
    float4 v = { ks[0], ks[1], ks[2], ks[3] };
    *reinterpret_cast<float4*>(Kspart + (size_t)slab * 4096 + bh * 64 + d0) = v;
  }
}

// ---------------- reduce 32 partials -> KVTx bf16 [bh][80][64]:
// rows 0..63 = KV^T (row e, col d), row 64 = Ksum, rows 65..79 = 0 (pre-memset).
__global__ __launch_bounds__(256) void kvreduce_kernel(
    const float* __restrict__ KVpart, const float* __restrict__ Kspart,
    ushort* __restrict__ KVTx) {
  const int idx = blockIdx.x * 256 + threadIdx.x;
  const int bh = idx >> 12;
  const int d = (idx >> 6) & 63;
  const int e = idx & 63;
  float s = 0.f;
#pragma unroll
  for (int c = 0; c < 32; ++c) s += KVpart[(size_t)c * (64 * 4096) + idx];
  KVTx[(size_t)bh * 5120 + e * 64 + d] = f2bf(s);
  if (idx < 64 * 64) {
    float s2 = 0.f;
#pragma unroll
    for (int c = 0; c < 32; ++c) s2 += Kspart[(size_t)c * 4096 + idx];
    KVTx[(size_t)(idx >> 6) * 5120 + 4096 + (idx & 63)] = f2bf(s2);
  }
}

// ---------------- Z via MFMA: per (bh, 128-row tile). 4 waves x 32 rows.
__global__ __launch_bounds__(256) void z_mfma_kernel(
    const ushort* __restrict__ Qp, const ushort* __restrict__ KVTx,
    ushort* __restrict__ Zn) {
  const int bh = blockIdx.y;
  const int b = bh >> 4, h = bh & 15;
  const int t = threadIdx.x;
  const int w = t >> 6, lane = t & 63;
  const int fr = lane & 15;
  const int kq = (lane >> 4) * 8;
  const int s0 = blockIdx.x * 128 + w * 32;

  const ushort* kvb = KVTx + (size_t)bh * 5120;
  bf16x8 bfrag[5][2];
#pragma unroll
  for (int ni = 0; ni < 5; ++ni)
#pragma unroll
    for (int ks = 0; ks < 2; ++ks)
      bfrag[ni][ks] = *reinterpret_cast<const bf16x8*>(kvb + (ni * 16 + fr) * 64 + ks * 32 + kq);

  f32x4 acc[2][5] = {};
  const size_t arow = (size_t)(b * SS + s0 + fr) * DM + h * 64;
#pragma unroll
  for (int mi = 0; mi < 2; ++mi) {
#pragma unroll
    for (int ks = 0; ks < 2; ++ks) {
      bf16x8 a = *reinterpret_cast<const bf16x8*>(Qp + arow + (size_t)mi * 16 * DM + ks * 32 + kq);
#pragma unroll
      for (int ni = 0; ni < 5; ++ni)
        acc[mi][ni] = __builtin_amdgcn_mfma_f32_16x16x32_bf16(a, bfrag[ni][ks], acc[mi][ni], 0, 0, 0);
    }
  }

#pragma unroll
  for (int mi = 0; mi < 2; ++mi) {
#pragma unroll
    for (int q = 0; q < 4; ++q) {
      const float dv = __shfl(acc[mi][4][q], lane & 48);
      const float inv = 1.f / (dv + 1e-6f);
      const int r = s0 + mi * 16 + (lane >> 4) * 4 + q;
      ushort* orow = Zn + (size_t)(b * SS + r) * DM + h * 64;
#pragma unroll
      for (int ni = 0; ni < 4; ++ni)
        orow[ni * 16 + fr] = f2bf(acc[mi][ni][q] * inv);
    }
  }
}

extern "C" void kernel_launch(void* const* d_in, const int* in_sizes, int n_in,
                              void* d_out, int out_size, void* d_ws, size_t ws_size,
                              hipStream_t stream) {
  const float* query = (const float*)d_in[0];
  const float* key_  = (const float*)d_in[1];
  const float* value = (const float*)d_in[2];
  const float* w_q = (const float*)d_in[3];
  const float* b_q = (const float*)d_in[4];
  const float* w_k = (const float*)d_in[5];
  const float* b_k = (const float*)d_in[6];
  const float* w_v = (const float*)d_in[7];
  const float* b_v = (const float*)d_in[8];
  const float* w_o = (const float*)d_in[9];
  const float* b_o = (const float*)d_in[10];

  char* ws = (char*)d_ws;
  const size_t NX = (size_t)MM * DM;            // 16,777,216
  ushort* Xq = (ushort*)ws; ws += NX * 2;
  ushort* Xk = (ushort*)ws; ws += NX * 2;
  ushort* Xv = (ushort*)ws; ws += NX * 2;
  ushort* Wq = (ushort*)ws; ws += (size_t)DM * DM * 2;
  ushort* Wk = (ushort*)ws; ws += (size_t)DM * DM * 2;
  ushort* Wv = (ushort*)ws; ws += (size_t)DM * DM * 2;
  ushort* Wo = (ushort*)ws; ws += (size_t)DM * DM * 2;
  ushort* Qp = (ushort*)ws; ws += NX * 2;
  ushort* Kp = (ushort*)ws; ws += NX * 2;
  ushort* Vp = (ushort*)ws; ws += NX * 2;
  ushort* KVTx = (ushort*)ws; ws += (size_t)64 * 80 * 64 * 2;   // 640 KiB
  ushort* Zn = (ushort*)ws; ws += NX * 2;

  // KV partials alias the dead Xq/Xk buffers (unused once Qp/Kp/Vp exist).
  float* KVpart = (float*)Xq;   // 32 MiB
  float* Kspart = (float*)Xk;   // 512 KiB

  cast3<<<3 * 1024, 256, 0, stream>>>(query, key_, value, Xq, Xk, Xv);
  cast_w4<<<4 * 1024, 256, 0, stream>>>(w_q, w_k, w_v, w_o, Wq, Wk, Wv, Wo);

  dim3 gg(DM / 256, MM / 256);   // (4, 64) = 256 blocks = 1/CU
  gemm8p<0><<<gg, 512, 0, stream>>>(Xq, Wq, b_q, Qp);
  gemm8p<0><<<gg, 512, 0, stream>>>(Xk, Wk, b_k, Kp);
  gemm8p<1><<<gg, 512, 0, stream>>>(Xv, Wv, b_v, Vp);

  kv_kernel<<<dim3(64, 8), 256, 0, stream>>>(Kp, Vp, KVpart, Kspart);
  hipMemsetAsync(KVTx, 0, (size_t)64 * 80 * 64 * 2, stream);   // zero rows 65..79
  kvreduce_kernel<<<1024, 256, 0, stream>>>(KVpart, Kspart, KVTx);
  z_mfma_kernel<<<dim3(32, 64), 256, 0, stream>>>(Qp, KVTx, Zn);

  gemm8p<2><<<gg, 512, 0, stream>>>(Zn, Wo, b_o, d_out);
}